// Round 7
// baseline (803.153 us; speedup 1.0000x reference)
//
#include <hip/hip_runtime.h>

// GCN 2-layer: N=200000, E=12800000, features 2 -> 16 -> 2.
// R2: rank trick -- aggregate only 2-dim vectors (before W1 / after W2).
// R4-R8: counting sort by dst bucket + LDS agg; agg ~150us invariant.
// R9/R10: window-grouping and LDS-window staging both failed -> the wall is
//     DIVERGENT-LANE serialization in per-CU pipes (TA / LDS): ~3 divergent
//     lane-ops per edge = 7-9 cyc/edge/CU in every variant. Cache level and
//     MLP depth are irrelevant to it.
// R11: remove lane divergence from the gather. Sort = (dst>>13 [25 sb],
//     src>>12 [49 grp]) phase A (1225 bins, 8.4 edges/bin/block -> write-amp
//     ~1.6) + phase B in-LDS sub-sort of each bin by src&4095 -> FULL-src
//     order within each superbucket. A wave's 64 consecutive edges then span
//     ~4 cache lines of the table (2.56 edges/src) -> TA coalesces the
//     gather; table slice streams through L1. Agg: 8192-node LDS acc (64KB,
//     2 blocks/CU) + 2 LDS atomics/edge + atomic flush. Entries are final-
//     format from phase A, so phase B is a pure permutation (skippable).
// R11b: resubmission -- R11 never ran (broker container failure, no compile
//     or test error). Re-audited LDS budgets / OOB / barriers; unchanged.

constexpr int N_NODES = 200000;
constexpr int N_EDGES = 12800000;

constexpr int SBS = 13;                              // 8192 dst / superbucket
constexpr int NSB = (N_NODES + 8191) / 8192;         // 25
constexpr int SGS = 12;                              // 4096 src / group
constexpr int NSGB = (N_NODES + 4095) / 4096;        // 49
constexpr int NBINB = NSB * NSGB;                    // 1225
constexpr int SAB = 1250;                            // phase-A sort blocks
constexpr int CHA = N_EDGES / SAB;                   // 10240 exactly
constexpr int RB = (NBINB + 255) / 256;              // 5
constexpr int CAPB = 11776;                          // bin cap (mean 10449 + ~13 sigma)
constexpr int DSEG = 24;
constexpr int ASEG = 24;

// ---------------- sort phase A ----------------

__global__ __launch_bounds__(256) void hist2_kernel(const int* __restrict__ src,
                                                    const int* __restrict__ dst,
                                                    unsigned short* __restrict__ bh16) {
    __shared__ unsigned h[NBINB];
    int t = threadIdx.x;
    for (int i = t; i < NBINB; i += 256) h[i] = 0;
    __syncthreads();
    int base = blockIdx.x * CHA;
    for (int e = base + t; e < base + CHA; e += 256) {
        unsigned d = (unsigned)dst[e];
        unsigned s = (unsigned)src[e];
        atomicAdd(&h[(d >> SBS) * NSGB + (s >> SGS)], 1u);
    }
    __syncthreads();
    unsigned short* row = bh16 + (size_t)blockIdx.x * NBINB;
    for (int i = t; i < NBINB; i += 256) row[i] = (unsigned short)h[i];
}

// Column scan of bh16[SAB][NBINB]: block handles 16 bins; thread: bin=t&15,
// chunk=t>>4 (16 chunks x 79 rows). Raw counts -> exclusive-over-blocks
// prefixes (u16) + binTotal (u32).
__global__ __launch_bounds__(256) void scan2_kernel(unsigned short* __restrict__ bh16,
                                                    unsigned* __restrict__ binTotal) {
    __shared__ unsigned psum[16][17];
    int t = threadIdx.x;
    int binL = t & 15, chunk = t >> 4;
    int bin = blockIdx.x * 16 + binL;
    bool ok = bin < NBINB;
    int r0 = chunk * 79, r1 = r0 + 79; if (r1 > SAB) r1 = SAB;
    unsigned s = 0;
    if (ok) for (int r = r0; r < r1; ++r) s += bh16[(size_t)r * NBINB + bin];
    psum[chunk][binL] = s;
    __syncthreads();
    if (chunk == 0 && ok) {
        unsigned run = 0;
        for (int c = 0; c < 16; ++c) { unsigned tmp = psum[c][binL]; psum[c][binL] = run; run += tmp; }
        binTotal[bin] = run;
    }
    __syncthreads();
    if (ok) {
        unsigned run = psum[chunk][binL];
        for (int r = r0; r < r1; ++r) {
            size_t idx = (size_t)r * NBINB + bin;
            unsigned tmp = bh16[idx];
            bh16[idx] = (unsigned short)run;
            run += tmp;
        }
    }
}

__global__ __launch_bounds__(256) void scan_bins2_kernel(const unsigned* __restrict__ binTotal,
                                                         unsigned* __restrict__ binStart) {
    __shared__ unsigned sh[256];
    int t = threadIdx.x;
    unsigned v[RB], run = 0;
#pragma unroll
    for (int j = 0; j < RB; j++) { int idx = RB * t + j; v[j] = (idx < NBINB) ? binTotal[idx] : 0u; }
#pragma unroll
    for (int j = 0; j < RB; j++) { unsigned tmp = v[j]; v[j] = run; run += tmp; }
    sh[t] = run;
    __syncthreads();
    for (int off = 1; off < 256; off <<= 1) {
        unsigned add = (t >= off) ? sh[t - off] : 0u;
        __syncthreads();
        sh[t] += add;
        __syncthreads();
    }
    unsigned excl = sh[t] - run;
#pragma unroll
    for (int j = 0; j < RB; j++) { int idx = RB * t + j; if (idx < NBINB) binStart[idx] = excl + v[j]; }
    if (t == 255) binStart[NBINB] = sh[255];
}

// Block-local counting sort by bin (LDS), in-order copy-out. Per-block counts
// reconstructed from scanned bh16 rows (R8 trick). Entry = FINAL format:
// src(18b) | (dst&8191) << 18  (31 bits).
__global__ __launch_bounds__(256) void scatterA_kernel(const int* __restrict__ src,
                                                       const int* __restrict__ dst,
                                                       const unsigned short* __restrict__ bh16,
                                                       const unsigned* __restrict__ binTotal,
                                                       const unsigned* __restrict__ binStart,
                                                       unsigned* __restrict__ sorted) {
    __shared__ unsigned s_cur[NBINB];
    __shared__ int      s_base[NBINB];
    __shared__ unsigned ssum[256];
    __shared__ unsigned ent[CHA];
    __shared__ unsigned short bkk[CHA];

    int t = threadIdx.x;
    int k = blockIdx.x;
    int base = k * CHA;
    const unsigned short* row  = bh16 + (size_t)k * NBINB;
    const unsigned short* rowN = bh16 + (size_t)(k + 1) * NBINB;
    bool last = (k == SAB - 1);

    unsigned v[RB], g0[RB], run = 0;
#pragma unroll
    for (int j = 0; j < RB; j++) {
        int idx = RB * t + j;
        if (idx < NBINB) {
            unsigned r0 = row[idx];
            unsigned r1 = last ? binTotal[idx] : (unsigned)rowN[idx];
            g0[j] = r0;
            v[j]  = r1 - r0;
        } else { g0[j] = 0; v[j] = 0; }
    }
#pragma unroll
    for (int j = 0; j < RB; j++) { unsigned tmp = v[j]; v[j] = run; run += tmp; }
    ssum[t] = run;
    __syncthreads();
    for (int off = 1; off < 256; off <<= 1) {
        unsigned add = (t >= off) ? ssum[t - off] : 0u;
        __syncthreads();
        ssum[t] += add;
        __syncthreads();
    }
    unsigned excl = ssum[t] - run;
#pragma unroll
    for (int j = 0; j < RB; j++) {
        int idx = RB * t + j;
        if (idx < NBINB) {
            unsigned st = excl + v[j];
            s_cur[idx]  = st;
            s_base[idx] = (int)(binStart[idx] + g0[j]) - (int)st;
        }
    }
    __syncthreads();

    for (int e = base + t; e < base + CHA; e += 256) {
        unsigned d = (unsigned)dst[e];
        unsigned s = (unsigned)src[e];
        unsigned b = (d >> SBS) * NSGB + (s >> SGS);
        unsigned lpos = atomicAdd(&s_cur[b], 1u);
        ent[lpos] = s | ((d & 8191u) << 18);
        bkk[lpos] = (unsigned short)b;
    }
    __syncthreads();

    for (int i = t; i < CHA; i += 256) {
        unsigned b = bkk[i];
        sorted[s_base[b] + i] = ent[i];
    }
}

// ---------------- sort phase B: in-bin sub-sort by src&4095 ----------------
// One block per bin. Bin staged in LDS (whole bin read before any write-back
// -> in-place safe). Oversized bins are skipped: entries are already final-
// format, so skipping only loses gather locality, never correctness.
__global__ __launch_bounds__(256) void sortbins_kernel(unsigned* __restrict__ sorted,
                                                       const unsigned* __restrict__ binStart) {
    __shared__ unsigned ent[CAPB];
    __shared__ unsigned hist[4096];
    __shared__ unsigned ssum[256];
    int t = threadIdx.x;
    int b = blockIdx.x;
    int base = binStart[b];
    int n = (int)binStart[b + 1] - base;
    if (n <= 0 || n > CAPB) return;

    for (int i = t; i < 4096; i += 256) hist[i] = 0;
    for (int i = t; i < n; i += 256) ent[i] = sorted[base + i];
    __syncthreads();
    for (int i = t; i < n; i += 256) atomicAdd(&hist[ent[i] & 4095u], 1u);
    __syncthreads();

    unsigned v[16], run = 0;
#pragma unroll
    for (int j = 0; j < 16; j++) v[j] = hist[16 * t + j];
#pragma unroll
    for (int j = 0; j < 16; j++) { unsigned tmp = v[j]; v[j] = run; run += tmp; }
    ssum[t] = run;
    __syncthreads();
    for (int off = 1; off < 256; off <<= 1) {
        unsigned add = (t >= off) ? ssum[t - off] : 0u;
        __syncthreads();
        ssum[t] += add;
        __syncthreads();
    }
    unsigned excl = ssum[t] - run;
#pragma unroll
    for (int j = 0; j < 16; j++) hist[16 * t + j] = excl + v[j];
    __syncthreads();

    // place: scattered global writes within this bin's ~43KB window (L2-hot)
    for (int i = t; i < n; i += 256) {
        unsigned w = ent[i];
        unsigned p = atomicAdd(&hist[w & 4095u], 1u);
        sorted[base + (int)p] = w;
    }
}

// ---------------- GCN phase ----------------

__global__ __launch_bounds__(256) void zero_kernel(unsigned* __restrict__ p, int n) {
    int i = blockIdx.x * 256 + threadIdx.x;
    if (i < n) p[i] = 0u;
}

__global__ __launch_bounds__(256) void deg2_kernel(const unsigned* __restrict__ sorted,
                                                   const unsigned* __restrict__ binStart,
                                                   unsigned* __restrict__ deg) {
    __shared__ unsigned cnt[8192];
    int t = threadIdx.x;
    for (int i = t; i < 8192; i += 256) cnt[i] = 0;
    __syncthreads();
    int sb = blockIdx.x / DSEG, s = blockIdx.x % DSEG;
    int s0 = binStart[sb * NSGB];
    int len = (int)binStart[(sb + 1) * NSGB] - s0;
    int e0 = s0 + (len * s) / DSEG;
    int e1 = s0 + (len * (s + 1)) / DSEG;
    int e = e0 + t;
    for (; e < e1 - 768; e += 1024) {
        unsigned w0 = sorted[e], w1 = sorted[e + 256], w2 = sorted[e + 512], w3 = sorted[e + 768];
        atomicAdd(&cnt[(w0 >> 18) & 8191u], 1u);
        atomicAdd(&cnt[(w1 >> 18) & 8191u], 1u);
        atomicAdd(&cnt[(w2 >> 18) & 8191u], 1u);
        atomicAdd(&cnt[(w3 >> 18) & 8191u], 1u);
    }
    for (; e < e1; e += 256)
        atomicAdd(&cnt[(sorted[e] >> 18) & 8191u], 1u);
    __syncthreads();
    int nb = sb << SBS;
    for (int i = t; i < 8192; i += 256) {
        int node = nb + i;
        if (node < N_NODES && cnt[i]) atomicAdd(&deg[node], cnt[i]);
    }
}

__global__ __launch_bounds__(256) void node1n_kernel(const float2* __restrict__ x,
                                                     unsigned* __restrict__ degdinv,
                                                     float2* __restrict__ u) {
    int i = blockIdx.x * 256 + threadIdx.x;
    if (i >= N_NODES) return;
    unsigned c = degdinv[i] + 1u;  // +1 self loop
    float di = rsqrtf((float)c);
    ((float*)degdinv)[i] = di;     // in-place u32 -> f32
    float2 xi = x[i];
    u[i] = make_float2(di * xi.x, di * xi.y);
}

// Aggregation over src-sorted superbucket segments: the gather's 64 lanes
// span ~4 cache lines (TA-coalesced); 2 LDS atomics per edge; atomic flush.
__global__ __launch_bounds__(256) void agg4_kernel(const unsigned* __restrict__ sorted,
                                                   const unsigned* __restrict__ binStart,
                                                   const float2* __restrict__ table,
                                                   float* __restrict__ acc) {
    __shared__ float ax[8192], ay[8192];
    int t = threadIdx.x;
    for (int i = t; i < 8192; i += 256) { ax[i] = 0.f; ay[i] = 0.f; }
    __syncthreads();
    int sb = blockIdx.x / ASEG, s = blockIdx.x % ASEG;
    int s0 = binStart[sb * NSGB];
    int len = (int)binStart[(sb + 1) * NSGB] - s0;
    int e0 = s0 + (len * s) / ASEG;
    int e1 = s0 + (len * (s + 1)) / ASEG;
    int e = e0 + t;
    for (; e < e1 - 768; e += 1024) {
        unsigned w0 = sorted[e], w1 = sorted[e + 256], w2 = sorted[e + 512], w3 = sorted[e + 768];
        float2 v0 = table[w0 & 0x3FFFFu];
        float2 v1 = table[w1 & 0x3FFFFu];
        float2 v2 = table[w2 & 0x3FFFFu];
        float2 v3 = table[w3 & 0x3FFFFu];
        unsigned l0 = (w0 >> 18) & 8191u, l1 = (w1 >> 18) & 8191u;
        unsigned l2 = (w2 >> 18) & 8191u, l3 = (w3 >> 18) & 8191u;
        atomicAdd(&ax[l0], v0.x); atomicAdd(&ay[l0], v0.y);
        atomicAdd(&ax[l1], v1.x); atomicAdd(&ay[l1], v1.y);
        atomicAdd(&ax[l2], v2.x); atomicAdd(&ay[l2], v2.y);
        atomicAdd(&ax[l3], v3.x); atomicAdd(&ay[l3], v3.y);
    }
    for (; e < e1; e += 256) {
        unsigned w = sorted[e];
        float2 v = table[w & 0x3FFFFu];
        unsigned l = (w >> 18) & 8191u;
        atomicAdd(&ax[l], v.x);
        atomicAdd(&ay[l], v.y);
    }
    __syncthreads();
    int nb = sb << SBS;
    for (int i = t; i < 8192; i += 256) {
        int node = nb + i;
        if (node < N_NODES) {
            float vx = ax[i], vy = ay[i];
            if (vx != 0.f || vy != 0.f) {
                unsafeAtomicAdd(&acc[2 * node],     vx);
                unsafeAtomicAdd(&acc[2 * node + 1], vy);
            }
        }
    }
}

__global__ __launch_bounds__(256) void node2n_kernel(const float2* __restrict__ acc,
                                                     float2* __restrict__ u,   // in: u, out: g2
                                                     const float* __restrict__ W1,
                                                     const float* __restrict__ b1,
                                                     const float* __restrict__ W2,
                                                     const float* __restrict__ dinv) {
    int i = blockIdx.x * 256 + threadIdx.x;
    if (i >= N_NODES) return;
    float di = dinv[i];
    float2 a = acc[i], uu = u[i];
    float c0 = di * (a.x + uu.x);
    float c1 = di * (a.y + uu.y);
    float a0 = 0.f, a1 = 0.f;
#pragma unroll
    for (int f = 0; f < 16; f++) {
        float o = fmaxf(c0 * W1[f] + c1 * W1[16 + f] + b1[f], 0.f);  // W1 (2,16)
        a0 += o * W2[2 * f];                                         // W2 (16,2)
        a1 += o * W2[2 * f + 1];
    }
    u[i] = make_float2(di * a0, di * a1);   // g2, same slot
}

__global__ __launch_bounds__(256) void node3n_kernel(const float2* __restrict__ acc,
                                                     const float2* __restrict__ g2,
                                                     const float* __restrict__ b2,
                                                     const float* __restrict__ dinv,
                                                     float2* __restrict__ out) {
    int i = blockIdx.x * 256 + threadIdx.x;
    if (i >= N_NODES) return;
    float di = dinv[i];
    float2 a = acc[i], g = g2[i];
    out[i] = make_float2(di * (a.x + g.x) + b2[0],
                         di * (a.y + g.y) + b2[1]);
}

// ---------------- fallback path (R2-style, needs only 8 MB ws) ----------------

__global__ __launch_bounds__(256) void fb_deg(const int* __restrict__ dst, int* __restrict__ degi) {
    int e = blockIdx.x * 256 + threadIdx.x;
    if (e < N_EDGES) atomicAdd(&degi[dst[e]], 1);
}
__global__ __launch_bounds__(256) void fb_node1(const float* __restrict__ x, const int* __restrict__ degi,
                                                float* __restrict__ dinv, float2* __restrict__ u) {
    int i = blockIdx.x * 256 + threadIdx.x;
    if (i >= N_NODES) return;
    float di = rsqrtf((float)(degi[i] + 1));
    dinv[i] = di;
    float2 xi = ((const float2*)x)[i];
    u[i] = make_float2(di * xi.x, di * xi.y);
}
__global__ __launch_bounds__(256) void fb_agg(const int* __restrict__ src, const int* __restrict__ dst,
                                              const float2* __restrict__ table, float* __restrict__ acc) {
    int e = blockIdx.x * 256 + threadIdx.x;
    if (e >= N_EDGES) return;
    float2 v = table[src[e]];
    size_t d = dst[e];
    unsafeAtomicAdd(&acc[2 * d], v.x);
    unsafeAtomicAdd(&acc[2 * d + 1], v.y);
}
__global__ __launch_bounds__(256) void fb_node2(const float2* __restrict__ u, const float2* __restrict__ A1,
                                                const float* __restrict__ W1, const float* __restrict__ b1,
                                                const float* __restrict__ W2, const float* __restrict__ dinv,
                                                float2* __restrict__ g2) {
    int i = blockIdx.x * 256 + threadIdx.x;
    if (i >= N_NODES) return;
    float di = dinv[i];
    float2 a = A1[i], uu = u[i];
    float c0 = di * (a.x + uu.x), c1 = di * (a.y + uu.y);
    float a0 = 0.f, a1 = 0.f;
#pragma unroll
    for (int f = 0; f < 16; f++) {
        float o = fmaxf(c0 * W1[f] + c1 * W1[16 + f] + b1[f], 0.f);
        a0 += o * W2[2 * f];
        a1 += o * W2[2 * f + 1];
    }
    g2[i] = make_float2(di * a0, di * a1);
}
__global__ __launch_bounds__(256) void fb_node3(const float2* __restrict__ g2, const float2* __restrict__ A2,
                                                const float* __restrict__ b2, const float* __restrict__ dinv,
                                                float2* __restrict__ out) {
    int i = blockIdx.x * 256 + threadIdx.x;
    if (i >= N_NODES) return;
    float di = dinv[i];
    float2 a = A2[i], g = g2[i];
    out[i] = make_float2(di * (a.x + g.x) + b2[0], di * (a.y + g.y) + b2[1]);
}

// ---------------- launcher ----------------

extern "C" void kernel_launch(void* const* d_in, const int* in_sizes, int n_in,
                              void* d_out, int out_size, void* d_ws, size_t ws_size,
                              hipStream_t stream) {
    const float* x  = (const float*)d_in[0];
    const float* W1 = (const float*)d_in[1];
    const float* b1 = (const float*)d_in[2];
    const float* W2 = (const float*)d_in[3];
    const float* b2 = (const float*)d_in[4];
    const int* ei   = (const int*)d_in[5];   // (2,E): row 0 = src, row 1 = dst
    const int* src = ei;
    const int* dst = ei + N_EDGES;
    float2* out = (float2*)d_out;

    // ws layout (4B words), total ~55.2 MB (< 61 MB proven available):
    //   sorted [E]                           12,800,000
    //   ovl    [1,000,000]  -- bh16 (1250*1225 u16 = 765,625 words) during
    //       sort; after scatterA: deg/dinv [0..200K) + acc [200K..600K)
    //       + u/g2 [600K..1M)
    //   binTotal [1225] ; binStart [1226+pad]
    const size_t need = ((size_t)N_EDGES + 1000000 + NBINB + 1232) * 4;

    if (ws_size >= need) {
        unsigned* sorted     = (unsigned*)d_ws;
        unsigned* ovl        = sorted + N_EDGES;
        unsigned short* bh16 = (unsigned short*)ovl;
        unsigned* deg        = ovl;
        float*    dinv       = (float*)deg;
        float*    acc        = (float*)(ovl + 200000);
        float2*   u          = (float2*)(ovl + 600000);
        unsigned* binTotal   = ovl + 1000000;
        unsigned* binStart   = binTotal + NBINB;

        hist2_kernel<<<SAB, 256, 0, stream>>>(src, dst, bh16);
        scan2_kernel<<<(NBINB + 15) / 16, 256, 0, stream>>>(bh16, binTotal);
        scan_bins2_kernel<<<1, 256, 0, stream>>>(binTotal, binStart);
        scatterA_kernel<<<SAB, 256, 0, stream>>>(src, dst, bh16, binTotal, binStart, sorted);
        sortbins_kernel<<<NBINB, 256, 0, stream>>>(sorted, binStart);
        // bh16 dead -> zero deg + acc overlay
        zero_kernel<<<(600000 + 255) / 256, 256, 0, stream>>>(deg, 600000);
        deg2_kernel<<<NSB * DSEG, 256, 0, stream>>>(sorted, binStart, deg);
        node1n_kernel<<<(N_NODES + 255) / 256, 256, 0, stream>>>((const float2*)x, deg, u);
        agg4_kernel<<<NSB * ASEG, 256, 0, stream>>>(sorted, binStart, u, acc);
        node2n_kernel<<<(N_NODES + 255) / 256, 256, 0, stream>>>((const float2*)acc, u, W1, b1, W2, dinv);
        zero_kernel<<<(400000 + 255) / 256, 256, 0, stream>>>((unsigned*)acc, 400000);
        agg4_kernel<<<NSB * ASEG, 256, 0, stream>>>(sorted, binStart, u, acc);
        node3n_kernel<<<(N_NODES + 255) / 256, 256, 0, stream>>>((const float2*)acc, u, b2, dinv, out);
    } else {
        // R2-style fallback (8 MB ws): global atomics, ~3.1 ms.
        float* ws = (float*)d_ws;
        int*   degi = (int*)ws;
        float* A1   = ws + N_NODES;
        float* A2   = A1 + 2 * (size_t)N_NODES;
        float* dinvF = A2 + 2 * (size_t)N_NODES;
        float2* uF  = (float2*)(dinvF + N_NODES);
        float2* g2F = uF + N_NODES;
        constexpr int EB = (N_EDGES + 255) / 256;
        constexpr int NB = (N_NODES + 255) / 256;
        (void)hipMemsetAsync(degi, 0, 5 * (size_t)N_NODES * sizeof(float), stream);
        fb_deg<<<EB, 256, 0, stream>>>(dst, degi);
        fb_node1<<<NB, 256, 0, stream>>>(x, degi, dinvF, uF);
        fb_agg<<<EB, 256, 0, stream>>>(src, dst, uF, A1);
        fb_node2<<<NB, 256, 0, stream>>>(uF, (const float2*)A1, W1, b1, W2, dinvF, g2F);
        fb_agg<<<EB, 256, 0, stream>>>(src, dst, g2F, A2);
        fb_node3<<<NB, 256, 0, stream>>>(g2F, (const float2*)A2, b2, dinvF, out);
    }
}

// Round 8
// 768.558 us; speedup vs baseline: 1.0450x; 1.0450x over previous
//
#include <hip/hip_runtime.h>

// GCN 2-layer: N=200000, E=12800000, features 2 -> 16 -> 2.
// R2: rank trick -- aggregate only 2-dim vectors (before W1 / after W2).
// R4-R8: counting sort by dst bucket + LDS agg; agg ~150us invariant
//     (fully-divergent gather = 1 L1-miss/edge, ~7cyc/edge/CU).
// R11: (dst>>13, src) full-src sort. Per-WAVE agg efficiency improved ~3x
//     (src-sorted gather TA-coalesces) but 64KB LDS acc -> 15.3% occupancy
//     -> latency fully exposed -> 210us. Flush atomics = 75MB WRITE_SIZE.
// R12: keep the src-sorted structure, pull the occupancy lever.
//     sb=4096 (SBS=12): acc 32KB -> ~5 blocks/CU; deg cnt 16KB -> 8/CU;
//     scatterA CHA=8000 -> 68KB -> 2/CU. Bins 49x49=2401. Within a bin the
//     gather walks one 32KB src-slice sequentially -> L1-resident.

constexpr int N_NODES = 200000;
constexpr int N_EDGES = 12800000;

constexpr int SBS = 12;                              // 4096 dst / superbucket
constexpr int NSB = (N_NODES + 4095) / 4096;         // 49
constexpr int SGS = 12;                              // 4096 src / group
constexpr int NSGB = (N_NODES + 4095) / 4096;        // 49
constexpr int NBINB = NSB * NSGB;                    // 2401
constexpr int S2B = 1600;                            // phase-A sort blocks
constexpr int CHA = N_EDGES / S2B;                   // 8000 exactly
constexpr int RB = (NBINB + 255) / 256;              // 10
constexpr int CAPB = 6656;                           // bin cap (mean 5369 + ~17 sigma)
constexpr int DSEG = 24;
constexpr int ASEG = 24;

// ---------------- sort phase A ----------------

__global__ __launch_bounds__(256) void hist2_kernel(const int* __restrict__ src,
                                                    const int* __restrict__ dst,
                                                    unsigned short* __restrict__ bh16) {
    __shared__ unsigned h[NBINB];
    int t = threadIdx.x;
    for (int i = t; i < NBINB; i += 256) h[i] = 0;
    __syncthreads();
    int base = blockIdx.x * CHA;
    for (int e = base + t; e < base + CHA; e += 256) {
        unsigned d = (unsigned)dst[e];
        unsigned s = (unsigned)src[e];
        atomicAdd(&h[(d >> SBS) * NSGB + (s >> SGS)], 1u);
    }
    __syncthreads();
    unsigned short* row = bh16 + (size_t)blockIdx.x * NBINB;
    for (int i = t; i < NBINB; i += 256) row[i] = (unsigned short)h[i];
}

// Column scan of bh16[S2B][NBINB]: block handles 16 bins; thread: bin=t&15,
// chunk=t>>4 (16 chunks x 100 rows). Raw counts -> exclusive-over-blocks
// prefixes (u16) + binTotal (u32).
__global__ __launch_bounds__(256) void scan2_kernel(unsigned short* __restrict__ bh16,
                                                    unsigned* __restrict__ binTotal) {
    __shared__ unsigned psum[16][17];
    int t = threadIdx.x;
    int binL = t & 15, chunk = t >> 4;
    int bin = blockIdx.x * 16 + binL;
    bool ok = bin < NBINB;
    int r0 = chunk * 100, r1 = r0 + 100; if (r1 > S2B) r1 = S2B;
    unsigned s = 0;
    if (ok) for (int r = r0; r < r1; ++r) s += bh16[(size_t)r * NBINB + bin];
    psum[chunk][binL] = s;
    __syncthreads();
    if (chunk == 0 && ok) {
        unsigned run = 0;
        for (int c = 0; c < 16; ++c) { unsigned tmp = psum[c][binL]; psum[c][binL] = run; run += tmp; }
        binTotal[bin] = run;
    }
    __syncthreads();
    if (ok) {
        unsigned run = psum[chunk][binL];
        for (int r = r0; r < r1; ++r) {
            size_t idx = (size_t)r * NBINB + bin;
            unsigned tmp = bh16[idx];
            bh16[idx] = (unsigned short)run;
            run += tmp;
        }
    }
}

__global__ __launch_bounds__(256) void scan_bins2_kernel(const unsigned* __restrict__ binTotal,
                                                         unsigned* __restrict__ binStart) {
    __shared__ unsigned sh[256];
    int t = threadIdx.x;
    unsigned v[RB], run = 0;
#pragma unroll
    for (int j = 0; j < RB; j++) { int idx = RB * t + j; v[j] = (idx < NBINB) ? binTotal[idx] : 0u; }
#pragma unroll
    for (int j = 0; j < RB; j++) { unsigned tmp = v[j]; v[j] = run; run += tmp; }
    sh[t] = run;
    __syncthreads();
    for (int off = 1; off < 256; off <<= 1) {
        unsigned add = (t >= off) ? sh[t - off] : 0u;
        __syncthreads();
        sh[t] += add;
        __syncthreads();
    }
    unsigned excl = sh[t] - run;
#pragma unroll
    for (int j = 0; j < RB; j++) { int idx = RB * t + j; if (idx < NBINB) binStart[idx] = excl + v[j]; }
    if (t == 255) binStart[NBINB] = sh[255];
}

// Block-local counting sort by bin (LDS), in-order copy-out. Per-block counts
// reconstructed from scanned bh16 rows (R8 trick). Entry = FINAL format:
// src(18b) | (dst&4095) << 18  (30 bits).
__global__ __launch_bounds__(256) void scatterA_kernel(const int* __restrict__ src,
                                                       const int* __restrict__ dst,
                                                       const unsigned short* __restrict__ bh16,
                                                       const unsigned* __restrict__ binTotal,
                                                       const unsigned* __restrict__ binStart,
                                                       unsigned* __restrict__ sorted) {
    __shared__ unsigned s_cur[NBINB];
    __shared__ int      s_base[NBINB];
    __shared__ unsigned ssum[256];
    __shared__ unsigned ent[CHA];
    __shared__ unsigned short bkk[CHA];

    int t = threadIdx.x;
    int k = blockIdx.x;
    int base = k * CHA;
    const unsigned short* row  = bh16 + (size_t)k * NBINB;
    const unsigned short* rowN = bh16 + (size_t)(k + 1) * NBINB;
    bool last = (k == S2B - 1);

    unsigned v[RB], g0[RB], run = 0;
#pragma unroll
    for (int j = 0; j < RB; j++) {
        int idx = RB * t + j;
        if (idx < NBINB) {
            unsigned r0 = row[idx];
            unsigned r1 = last ? binTotal[idx] : (unsigned)rowN[idx];
            g0[j] = r0;
            v[j]  = r1 - r0;
        } else { g0[j] = 0; v[j] = 0; }
    }
#pragma unroll
    for (int j = 0; j < RB; j++) { unsigned tmp = v[j]; v[j] = run; run += tmp; }
    ssum[t] = run;
    __syncthreads();
    for (int off = 1; off < 256; off <<= 1) {
        unsigned add = (t >= off) ? ssum[t - off] : 0u;
        __syncthreads();
        ssum[t] += add;
        __syncthreads();
    }
    unsigned excl = ssum[t] - run;
#pragma unroll
    for (int j = 0; j < RB; j++) {
        int idx = RB * t + j;
        if (idx < NBINB) {
            unsigned st = excl + v[j];
            s_cur[idx]  = st;
            s_base[idx] = (int)(binStart[idx] + g0[j]) - (int)st;
        }
    }
    __syncthreads();

    for (int e = base + t; e < base + CHA; e += 256) {
        unsigned d = (unsigned)dst[e];
        unsigned s = (unsigned)src[e];
        unsigned b = (d >> SBS) * NSGB + (s >> SGS);
        unsigned lpos = atomicAdd(&s_cur[b], 1u);
        ent[lpos] = s | ((d & 4095u) << 18);
        bkk[lpos] = (unsigned short)b;
    }
    __syncthreads();

    for (int i = t; i < CHA; i += 256) {
        unsigned b = bkk[i];
        sorted[s_base[b] + i] = ent[i];
    }
}

// ---------------- sort phase B: in-bin sub-sort by src&4095 ----------------
// One block per bin. Bin staged in LDS (whole bin read before any write-back
// -> in-place safe). Oversized bins are skipped: entries are already final-
// format, so skipping only loses gather locality, never correctness.
__global__ __launch_bounds__(256) void sortbins_kernel(unsigned* __restrict__ sorted,
                                                       const unsigned* __restrict__ binStart) {
    __shared__ unsigned ent[CAPB];
    __shared__ unsigned hist[4096];
    __shared__ unsigned ssum[256];
    int t = threadIdx.x;
    int b = blockIdx.x;
    int base = binStart[b];
    int n = (int)binStart[b + 1] - base;
    if (n <= 0 || n > CAPB) return;

    for (int i = t; i < 4096; i += 256) hist[i] = 0;
    for (int i = t; i < n; i += 256) ent[i] = sorted[base + i];
    __syncthreads();
    for (int i = t; i < n; i += 256) atomicAdd(&hist[ent[i] & 4095u], 1u);
    __syncthreads();

    unsigned v[16], run = 0;
#pragma unroll
    for (int j = 0; j < 16; j++) v[j] = hist[16 * t + j];
#pragma unroll
    for (int j = 0; j < 16; j++) { unsigned tmp = v[j]; v[j] = run; run += tmp; }
    ssum[t] = run;
    __syncthreads();
    for (int off = 1; off < 256; off <<= 1) {
        unsigned add = (t >= off) ? ssum[t - off] : 0u;
        __syncthreads();
        ssum[t] += add;
        __syncthreads();
    }
    unsigned excl = ssum[t] - run;
#pragma unroll
    for (int j = 0; j < 16; j++) hist[16 * t + j] = excl + v[j];
    __syncthreads();

    // place: scattered global writes within this bin's ~21KB window (L2-hot)
    for (int i = t; i < n; i += 256) {
        unsigned w = ent[i];
        unsigned p = atomicAdd(&hist[w & 4095u], 1u);
        sorted[base + (int)p] = w;
    }
}

// ---------------- GCN phase ----------------

__global__ __launch_bounds__(256) void zero_kernel(unsigned* __restrict__ p, int n) {
    int i = blockIdx.x * 256 + threadIdx.x;
    if (i < n) p[i] = 0u;
}

__global__ __launch_bounds__(256) void deg2_kernel(const unsigned* __restrict__ sorted,
                                                   const unsigned* __restrict__ binStart,
                                                   unsigned* __restrict__ deg) {
    __shared__ unsigned cnt[4096];
    int t = threadIdx.x;
    for (int i = t; i < 4096; i += 256) cnt[i] = 0;
    __syncthreads();
    int sb = blockIdx.x / DSEG, s = blockIdx.x % DSEG;
    int s0 = binStart[sb * NSGB];
    int len = (int)binStart[(sb + 1) * NSGB] - s0;
    int e0 = s0 + (len * s) / DSEG;
    int e1 = s0 + (len * (s + 1)) / DSEG;
    int e = e0 + t;
    for (; e < e1 - 768; e += 1024) {
        unsigned w0 = sorted[e], w1 = sorted[e + 256], w2 = sorted[e + 512], w3 = sorted[e + 768];
        atomicAdd(&cnt[(w0 >> 18) & 4095u], 1u);
        atomicAdd(&cnt[(w1 >> 18) & 4095u], 1u);
        atomicAdd(&cnt[(w2 >> 18) & 4095u], 1u);
        atomicAdd(&cnt[(w3 >> 18) & 4095u], 1u);
    }
    for (; e < e1; e += 256)
        atomicAdd(&cnt[(sorted[e] >> 18) & 4095u], 1u);
    __syncthreads();
    int nb = sb << SBS;
    for (int i = t; i < 4096; i += 256) {
        int node = nb + i;
        if (node < N_NODES && cnt[i]) atomicAdd(&deg[node], cnt[i]);
    }
}

__global__ __launch_bounds__(256) void node1n_kernel(const float2* __restrict__ x,
                                                     unsigned* __restrict__ degdinv,
                                                     float2* __restrict__ u) {
    int i = blockIdx.x * 256 + threadIdx.x;
    if (i >= N_NODES) return;
    unsigned c = degdinv[i] + 1u;  // +1 self loop
    float di = rsqrtf((float)c);
    ((float*)degdinv)[i] = di;     // in-place u32 -> f32
    float2 xi = x[i];
    u[i] = make_float2(di * xi.x, di * xi.y);
}

// Aggregation over src-sorted superbucket segments: 64 consecutive edges span
// ~7 table lines (TA-coalesced) and each bin's 32KB src-slice is L1-resident;
// 2 LDS atomics per edge; atomic flush into L2-resident acc.
__global__ __launch_bounds__(256) void agg5_kernel(const unsigned* __restrict__ sorted,
                                                   const unsigned* __restrict__ binStart,
                                                   const float2* __restrict__ table,
                                                   float* __restrict__ acc) {
    __shared__ float ax[4096], ay[4096];
    int t = threadIdx.x;
    for (int i = t; i < 4096; i += 256) { ax[i] = 0.f; ay[i] = 0.f; }
    __syncthreads();
    int sb = blockIdx.x / ASEG, s = blockIdx.x % ASEG;
    int s0 = binStart[sb * NSGB];
    int len = (int)binStart[(sb + 1) * NSGB] - s0;
    int e0 = s0 + (len * s) / ASEG;
    int e1 = s0 + (len * (s + 1)) / ASEG;
    int e = e0 + t;
    for (; e < e1 - 768; e += 1024) {
        unsigned w0 = sorted[e], w1 = sorted[e + 256], w2 = sorted[e + 512], w3 = sorted[e + 768];
        float2 v0 = table[w0 & 0x3FFFFu];
        float2 v1 = table[w1 & 0x3FFFFu];
        float2 v2 = table[w2 & 0x3FFFFu];
        float2 v3 = table[w3 & 0x3FFFFu];
        unsigned l0 = (w0 >> 18) & 4095u, l1 = (w1 >> 18) & 4095u;
        unsigned l2 = (w2 >> 18) & 4095u, l3 = (w3 >> 18) & 4095u;
        atomicAdd(&ax[l0], v0.x); atomicAdd(&ay[l0], v0.y);
        atomicAdd(&ax[l1], v1.x); atomicAdd(&ay[l1], v1.y);
        atomicAdd(&ax[l2], v2.x); atomicAdd(&ay[l2], v2.y);
        atomicAdd(&ax[l3], v3.x); atomicAdd(&ay[l3], v3.y);
    }
    for (; e < e1; e += 256) {
        unsigned w = sorted[e];
        float2 v = table[w & 0x3FFFFu];
        unsigned l = (w >> 18) & 4095u;
        atomicAdd(&ax[l], v.x);
        atomicAdd(&ay[l], v.y);
    }
    __syncthreads();
    int nb = sb << SBS;
    for (int i = t; i < 4096; i += 256) {
        int node = nb + i;
        if (node < N_NODES) {
            float vx = ax[i], vy = ay[i];
            if (vx != 0.f || vy != 0.f) {
                unsafeAtomicAdd(&acc[2 * node],     vx);
                unsafeAtomicAdd(&acc[2 * node + 1], vy);
            }
        }
    }
}

__global__ __launch_bounds__(256) void node2n_kernel(const float2* __restrict__ acc,
                                                     float2* __restrict__ u,   // in: u, out: g2
                                                     const float* __restrict__ W1,
                                                     const float* __restrict__ b1,
                                                     const float* __restrict__ W2,
                                                     const float* __restrict__ dinv) {
    int i = blockIdx.x * 256 + threadIdx.x;
    if (i >= N_NODES) return;
    float di = dinv[i];
    float2 a = acc[i], uu = u[i];
    float c0 = di * (a.x + uu.x);
    float c1 = di * (a.y + uu.y);
    float a0 = 0.f, a1 = 0.f;
#pragma unroll
    for (int f = 0; f < 16; f++) {
        float o = fmaxf(c0 * W1[f] + c1 * W1[16 + f] + b1[f], 0.f);  // W1 (2,16)
        a0 += o * W2[2 * f];                                         // W2 (16,2)
        a1 += o * W2[2 * f + 1];
    }
    u[i] = make_float2(di * a0, di * a1);   // g2, same slot
}

__global__ __launch_bounds__(256) void node3n_kernel(const float2* __restrict__ acc,
                                                     const float2* __restrict__ g2,
                                                     const float* __restrict__ b2,
                                                     const float* __restrict__ dinv,
                                                     float2* __restrict__ out) {
    int i = blockIdx.x * 256 + threadIdx.x;
    if (i >= N_NODES) return;
    float di = dinv[i];
    float2 a = acc[i], g = g2[i];
    out[i] = make_float2(di * (a.x + g.x) + b2[0],
                         di * (a.y + g.y) + b2[1]);
}

// ---------------- fallback path (R2-style, needs only 8 MB ws) ----------------

__global__ __launch_bounds__(256) void fb_deg(const int* __restrict__ dst, int* __restrict__ degi) {
    int e = blockIdx.x * 256 + threadIdx.x;
    if (e < N_EDGES) atomicAdd(&degi[dst[e]], 1);
}
__global__ __launch_bounds__(256) void fb_node1(const float* __restrict__ x, const int* __restrict__ degi,
                                                float* __restrict__ dinv, float2* __restrict__ u) {
    int i = blockIdx.x * 256 + threadIdx.x;
    if (i >= N_NODES) return;
    float di = rsqrtf((float)(degi[i] + 1));
    dinv[i] = di;
    float2 xi = ((const float2*)x)[i];
    u[i] = make_float2(di * xi.x, di * xi.y);
}
__global__ __launch_bounds__(256) void fb_agg(const int* __restrict__ src, const int* __restrict__ dst,
                                              const float2* __restrict__ table, float* __restrict__ acc) {
    int e = blockIdx.x * 256 + threadIdx.x;
    if (e >= N_EDGES) return;
    float2 v = table[src[e]];
    size_t d = dst[e];
    unsafeAtomicAdd(&acc[2 * d], v.x);
    unsafeAtomicAdd(&acc[2 * d + 1], v.y);
}
__global__ __launch_bounds__(256) void fb_node2(const float2* __restrict__ u, const float2* __restrict__ A1,
                                                const float* __restrict__ W1, const float* __restrict__ b1,
                                                const float* __restrict__ W2, const float* __restrict__ dinv,
                                                float2* __restrict__ g2) {
    int i = blockIdx.x * 256 + threadIdx.x;
    if (i >= N_NODES) return;
    float di = dinv[i];
    float2 a = A1[i], uu = u[i];
    float c0 = di * (a.x + uu.x), c1 = di * (a.y + uu.y);
    float a0 = 0.f, a1 = 0.f;
#pragma unroll
    for (int f = 0; f < 16; f++) {
        float o = fmaxf(c0 * W1[f] + c1 * W1[16 + f] + b1[f], 0.f);
        a0 += o * W2[2 * f];
        a1 += o * W2[2 * f + 1];
    }
    g2[i] = make_float2(di * a0, di * a1);
}
__global__ __launch_bounds__(256) void fb_node3(const float2* __restrict__ g2, const float2* __restrict__ A2,
                                                const float* __restrict__ b2, const float* __restrict__ dinv,
                                                float2* __restrict__ out) {
    int i = blockIdx.x * 256 + threadIdx.x;
    if (i >= N_NODES) return;
    float di = dinv[i];
    float2 a = A2[i], g = g2[i];
    out[i] = make_float2(di * (a.x + g.x) + b2[0], di * (a.y + g.y) + b2[1]);
}

// ---------------- launcher ----------------

extern "C" void kernel_launch(void* const* d_in, const int* in_sizes, int n_in,
                              void* d_out, int out_size, void* d_ws, size_t ws_size,
                              hipStream_t stream) {
    const float* x  = (const float*)d_in[0];
    const float* W1 = (const float*)d_in[1];
    const float* b1 = (const float*)d_in[2];
    const float* W2 = (const float*)d_in[3];
    const float* b2 = (const float*)d_in[4];
    const int* ei   = (const int*)d_in[5];   // (2,E): row 0 = src, row 1 = dst
    const int* src = ei;
    const int* dst = ei + N_EDGES;
    float2* out = (float2*)d_out;

    // ws layout (4B words), total ~58.9 MB (< 61.6 MB proven available):
    //   sorted [E]                           12,800,000
    //   region [1,920,800]  -- bh16 (1600*2401 u16 = 1,920,800 u32 words)
    //       during sort; after scatterA: deg/dinv [0..200K) + acc
    //       [200K..600K) + u/g2 [600K..1M)
    //   binTotal [2401] ; binStart [2402+pad -> 2416]
    const size_t need = ((size_t)N_EDGES + 1920800 + NBINB + 2416) * 4;

    if (ws_size >= need) {
        unsigned* sorted     = (unsigned*)d_ws;
        unsigned* ovl        = sorted + N_EDGES;
        unsigned short* bh16 = (unsigned short*)ovl;
        unsigned* deg        = ovl;
        float*    dinv       = (float*)deg;
        float*    acc        = (float*)(ovl + 200000);
        float2*   u          = (float2*)(ovl + 600000);
        unsigned* binTotal   = ovl + 1920800;
        unsigned* binStart   = binTotal + NBINB;

        hist2_kernel<<<S2B, 256, 0, stream>>>(src, dst, bh16);
        scan2_kernel<<<(NBINB + 15) / 16, 256, 0, stream>>>(bh16, binTotal);
        scan_bins2_kernel<<<1, 256, 0, stream>>>(binTotal, binStart);
        scatterA_kernel<<<S2B, 256, 0, stream>>>(src, dst, bh16, binTotal, binStart, sorted);
        sortbins_kernel<<<NBINB, 256, 0, stream>>>(sorted, binStart);
        // bh16 dead -> zero deg + acc overlay
        zero_kernel<<<(600000 + 255) / 256, 256, 0, stream>>>(deg, 600000);
        deg2_kernel<<<NSB * DSEG, 256, 0, stream>>>(sorted, binStart, deg);
        node1n_kernel<<<(N_NODES + 255) / 256, 256, 0, stream>>>((const float2*)x, deg, u);
        agg5_kernel<<<NSB * ASEG, 256, 0, stream>>>(sorted, binStart, u, acc);
        node2n_kernel<<<(N_NODES + 255) / 256, 256, 0, stream>>>((const float2*)acc, u, W1, b1, W2, dinv);
        zero_kernel<<<(400000 + 255) / 256, 256, 0, stream>>>((unsigned*)acc, 400000);
        agg5_kernel<<<NSB * ASEG, 256, 0, stream>>>(sorted, binStart, u, acc);
        node3n_kernel<<<(N_NODES + 255) / 256, 256, 0, stream>>>((const float2*)acc, u, b2, dinv, out);
    } else {
        // R2-style fallback (8 MB ws): global atomics, ~3.1 ms.
        float* ws = (float*)d_ws;
        int*   degi = (int*)ws;
        float* A1   = ws + N_NODES;
        float* A2   = A1 + 2 * (size_t)N_NODES;
        float* dinvF = A2 + 2 * (size_t)N_NODES;
        float2* uF  = (float2*)(dinvF + N_NODES);
        float2* g2F = uF + N_NODES;
        constexpr int EB = (N_EDGES + 255) / 256;
        constexpr int NB = (N_NODES + 255) / 256;
        (void)hipMemsetAsync(degi, 0, 5 * (size_t)N_NODES * sizeof(float), stream);
        fb_deg<<<EB, 256, 0, stream>>>(dst, degi);
        fb_node1<<<NB, 256, 0, stream>>>(x, degi, dinvF, uF);
        fb_agg<<<EB, 256, 0, stream>>>(src, dst, uF, A1);
        fb_node2<<<NB, 256, 0, stream>>>(uF, (const float2*)A1, W1, b1, W2, dinvF, g2F);
        fb_agg<<<EB, 256, 0, stream>>>(src, dst, g2F, A2);
        fb_node3<<<NB, 256, 0, stream>>>(g2F, (const float2*)A2, b2, dinvF, out);
    }
}

// Round 9
// 520.249 us; speedup vs baseline: 1.5438x; 1.4773x over previous
//
#include <hip/hip_runtime.h>

// GCN 2-layer: N=200000, E=12800000, features 2 -> 16 -> 2.
// R2: rank trick -- aggregate only 2-dim vectors (before W1 / after W2).
// R4-R12 summary: every agg variant carried 3 divergent-address lane-ops per
//     edge (1 gather + 2 LDS-atomic accumulate) and every one cost 7-10
//     cyc/edge/CU regardless of occupancy (15-65%), gather locality (random /
//     windowed / LDS / src-sorted), or accumulator placement. The invariant
//     is the COUNT of divergent lane-ops; each costs ~2.5 cyc of per-CU
//     address processing.
// R13: cut 3 -> 1. Full-dst sort: proven R8 phase A (2048-block counting
//     sort into 782 256-node buckets) + new phase B (per-bucket in-LDS
//     counting sort by dst&255) -> per-node contiguous runs + nodeStart[N].
//     Aggregation = one wave per node (avg deg 64 = wave size): coalesced
//     run read, divergent gather ONLY, register accumulate, shfl_xor
//     butterfly, single write. No accumulator atomics, no partials, no
//     flush, no zeroing; deg = nodeStart diff (deg kernel deleted); MLP
//     fused into layer-1 epilogue. 10 kernels -> 8.

constexpr int N_NODES = 200000;
constexpr int N_EDGES = 12800000;
constexpr int RANGE_SHIFT = 8;                       // 256 nodes / bucket
constexpr int K_BUCKETS = (N_NODES + 255) / 256;     // 782
constexpr int SORT_BLOCKS = 2048;
constexpr int CHUNK = N_EDGES / SORT_BLOCKS;         // 6250 exactly
constexpr int SCAN_R = SORT_BLOCKS / 256;            // 8
constexpr int CAPB = 18432;                          // bucket cap: mean 16368 + 16 sigma

// ---------------- sort phase A (verbatim R8, proven) ----------------

__global__ __launch_bounds__(256) void hist_kernel(const int* __restrict__ dst,
                                                   unsigned* __restrict__ blockHist) {
    __shared__ unsigned h[K_BUCKETS];
    for (int i = threadIdx.x; i < K_BUCKETS; i += 256) h[i] = 0;
    __syncthreads();
    int base = blockIdx.x * CHUNK;
    for (int e = base + threadIdx.x; e < base + CHUNK; e += 256)
        atomicAdd(&h[((unsigned)dst[e]) >> RANGE_SHIFT], 1u);
    __syncthreads();
    unsigned* row = blockHist + (size_t)blockIdx.x * K_BUCKETS;
    for (int i = threadIdx.x; i < K_BUCKETS; i += 256) row[i] = h[i];
}

__global__ __launch_bounds__(256) void scan_perblock_kernel(unsigned* __restrict__ blockHist,
                                                            unsigned* __restrict__ bucketTotal) {
    int b = blockIdx.x, t = threadIdx.x;
    unsigned v[SCAN_R], run = 0;
#pragma unroll
    for (int j = 0; j < SCAN_R; j++) v[j] = blockHist[(size_t)(SCAN_R * t + j) * K_BUCKETS + b];
#pragma unroll
    for (int j = 0; j < SCAN_R; j++) { unsigned tmp = v[j]; v[j] = run; run += tmp; }
    __shared__ unsigned sh[256];
    sh[t] = run;
    __syncthreads();
    for (int off = 1; off < 256; off <<= 1) {
        unsigned add = (t >= off) ? sh[t - off] : 0u;
        __syncthreads();
        sh[t] += add;
        __syncthreads();
    }
    unsigned excl = sh[t] - run;
#pragma unroll
    for (int j = 0; j < SCAN_R; j++)
        blockHist[(size_t)(SCAN_R * t + j) * K_BUCKETS + b] = excl + v[j];
    if (t == 255) bucketTotal[b] = sh[255];
}

__global__ __launch_bounds__(1024) void scan_buckets_kernel(const unsigned* __restrict__ bucketTotal,
                                                            unsigned* __restrict__ bucketStart) {
    __shared__ unsigned sh[1024];
    int t = threadIdx.x;
    unsigned v = (t < K_BUCKETS) ? bucketTotal[t] : 0u;
    sh[t] = v;
    __syncthreads();
    for (int off = 1; off < 1024; off <<= 1) {
        unsigned add = (t >= off) ? sh[t - off] : 0u;
        __syncthreads();
        sh[t] += add;
        __syncthreads();
    }
    if (t < K_BUCKETS) bucketStart[t] = sh[t] - v;
    if (t == K_BUCKETS - 1) bucketStart[K_BUCKETS] = sh[t];
}

// Block-local counting sort in LDS, in-order coalesced copy-out. Packed 4B
// entry: src (18b) | local_dst (8b) << 18. Per-block counts reconstructed
// from scanned blockHist rows (R8 trick).
__global__ __launch_bounds__(256) void scatter_kernel(const int* __restrict__ src,
                                                      const int* __restrict__ dst,
                                                      const unsigned* __restrict__ blockHist,
                                                      const unsigned* __restrict__ bucketTotal,
                                                      const unsigned* __restrict__ bucketStart,
                                                      unsigned* __restrict__ sorted) {
    __shared__ unsigned s_cur[K_BUCKETS];
    __shared__ int      s_base[K_BUCKETS];
    __shared__ unsigned ssum[256];
    __shared__ unsigned ent[CHUNK];
    __shared__ unsigned short bk[CHUNK];

    int t = threadIdx.x;
    int k = blockIdx.x;
    int base = k * CHUNK;
    const unsigned* row  = blockHist + (size_t)k * K_BUCKETS;
    const unsigned* rowN = blockHist + (size_t)(k + 1) * K_BUCKETS;
    bool last = (k == SORT_BLOCKS - 1);

    unsigned v[4], g0[4], run = 0;
#pragma unroll
    for (int j = 0; j < 4; j++) {
        int idx = 4 * t + j;
        if (idx < K_BUCKETS) {
            unsigned r0 = row[idx];
            unsigned r1 = last ? bucketTotal[idx] : rowN[idx];
            g0[j] = r0;
            v[j]  = r1 - r0;
        } else { g0[j] = 0; v[j] = 0; }
    }
#pragma unroll
    for (int j = 0; j < 4; j++) { unsigned tmp = v[j]; v[j] = run; run += tmp; }
    ssum[t] = run;
    __syncthreads();
    for (int off = 1; off < 256; off <<= 1) {
        unsigned add = (t >= off) ? ssum[t - off] : 0u;
        __syncthreads();
        ssum[t] += add;
        __syncthreads();
    }
    unsigned excl = ssum[t] - run;
#pragma unroll
    for (int j = 0; j < 4; j++) {
        int idx = 4 * t + j;
        if (idx < K_BUCKETS) {
            unsigned st = excl + v[j];
            s_cur[idx]  = st;
            s_base[idx] = (int)(bucketStart[idx] + g0[j]) - (int)st;
        }
    }
    __syncthreads();

    for (int e = base + t; e < base + CHUNK; e += 256) {
        unsigned d = (unsigned)dst[e];
        unsigned s = (unsigned)src[e];
        unsigned b = d >> RANGE_SHIFT;
        unsigned lpos = atomicAdd(&s_cur[b], 1u);
        ent[lpos] = s | ((d & 255u) << 18);
        bk[lpos] = (unsigned short)b;
    }
    __syncthreads();

    for (int i = t; i < CHUNK; i += 256) {
        unsigned b = bk[i];
        sorted[s_base[b] + i] = ent[i];
    }
}

// ---------------- sort phase B: per-bucket sort by local dst ----------------
// One block per bucket. Whole bucket staged into LDS before any write-back
// (in-place safe). Emits nodeStart[node] = bucket base + exclusive prefix.
// CAPB = mean + 16 sigma; binomial tail ~1e-55 and the input is fixed.
__global__ __launch_bounds__(256) void sortbins_kernel(unsigned* __restrict__ sorted,
                                                       const unsigned* __restrict__ bucketStart,
                                                       unsigned* __restrict__ nodeStart) {
    __shared__ unsigned ent[CAPB];
    __shared__ unsigned hist[256];
    __shared__ unsigned cur[256];
    __shared__ unsigned ssum[256];
    int t = threadIdx.x, b = blockIdx.x;
    int base = (int)bucketStart[b];
    int n = (int)bucketStart[b + 1] - base;
    if (n > CAPB) return;  // block-uniform; astronomically improbable

    hist[t] = 0;
    __syncthreads();
    for (int i = t; i < n; i += 256) {
        unsigned w = sorted[base + i];
        ent[i] = w;
        atomicAdd(&hist[(w >> 18) & 255u], 1u);
    }
    __syncthreads();
    unsigned v = hist[t];
    ssum[t] = v;
    __syncthreads();
    for (int off = 1; off < 256; off <<= 1) {
        unsigned add = (t >= off) ? ssum[t - off] : 0u;
        __syncthreads();
        ssum[t] += add;
        __syncthreads();
    }
    unsigned excl = ssum[t] - v;
    cur[t] = excl;
    int node = (b << RANGE_SHIFT) + t;
    if (node < N_NODES) nodeStart[node] = (unsigned)(base + (int)excl);
    if (b == K_BUCKETS - 1 && t == 0) nodeStart[N_NODES] = bucketStart[K_BUCKETS];
    __syncthreads();
    // place: scattered global writes confined to this bucket's ~66KB window
    for (int i = t; i < n; i += 256) {
        unsigned w = ent[i];
        unsigned p = atomicAdd(&cur[(w >> 18) & 255u], 1u);
        sorted[base + (int)p] = w;
    }
}

// ---------------- GCN phase ----------------

__global__ __launch_bounds__(256) void node1w_kernel(const float2* __restrict__ x,
                                                     const unsigned* __restrict__ nodeStart,
                                                     float* __restrict__ dinv,
                                                     float2* __restrict__ u) {
    int i = blockIdx.x * 256 + threadIdx.x;
    if (i >= N_NODES) return;
    unsigned deg = nodeStart[i + 1] - nodeStart[i] + 1u;  // +1 self loop
    float di = rsqrtf((float)deg);
    dinv[i] = di;
    float2 xi = x[i];
    u[i] = make_float2(di * xi.x, di * xi.y);
}

// Layer 1: one wave per node. Coalesced run read, divergent gather ONLY,
// register accumulate, butterfly reduce, fused 2->16->2 MLP epilogue.
__global__ __launch_bounds__(256) void aggw1_kernel(const unsigned* __restrict__ sorted,
                                                    const unsigned* __restrict__ nodeStart,
                                                    const float2* __restrict__ u,
                                                    const float* __restrict__ dinv,
                                                    const float* __restrict__ W1,
                                                    const float* __restrict__ b1,
                                                    const float* __restrict__ W2,
                                                    float2* __restrict__ g2) {
    int i = blockIdx.x * 4 + (threadIdx.x >> 6);
    if (i >= N_NODES) return;
    int lane = threadIdx.x & 63;
    int e0 = (int)nodeStart[i], e1 = (int)nodeStart[i + 1];
    float ax = 0.f, ay = 0.f;
    for (int k = e0 + lane; k < e1; k += 64) {
        unsigned w = sorted[k];
        float2 v = u[w & 0x3FFFFu];
        ax += v.x; ay += v.y;
    }
#pragma unroll
    for (int off = 32; off; off >>= 1) {
        ax += __shfl_xor(ax, off);
        ay += __shfl_xor(ay, off);
    }
    float di = dinv[i];
    float2 uu = u[i];
    float c0 = di * (ax + uu.x);
    float c1 = di * (ay + uu.y);
    float a0 = 0.f, a1 = 0.f;
    if (lane < 16) {
        float o = fmaxf(c0 * W1[lane] + c1 * W1[16 + lane] + b1[lane], 0.f);  // W1 (2,16)
        a0 = o * W2[2 * lane];                                                // W2 (16,2)
        a1 = o * W2[2 * lane + 1];
    }
#pragma unroll
    for (int off = 8; off; off >>= 1) {
        a0 += __shfl_xor(a0, off);
        a1 += __shfl_xor(a1, off);
    }
    if (lane == 0) g2[i] = make_float2(di * a0, di * a1);
}

// Layer 2: same core over table=g2; bias epilogue.
__global__ __launch_bounds__(256) void aggw2_kernel(const unsigned* __restrict__ sorted,
                                                    const unsigned* __restrict__ nodeStart,
                                                    const float2* __restrict__ g2,
                                                    const float* __restrict__ dinv,
                                                    const float* __restrict__ b2,
                                                    float2* __restrict__ out) {
    int i = blockIdx.x * 4 + (threadIdx.x >> 6);
    if (i >= N_NODES) return;
    int lane = threadIdx.x & 63;
    int e0 = (int)nodeStart[i], e1 = (int)nodeStart[i + 1];
    float ax = 0.f, ay = 0.f;
    for (int k = e0 + lane; k < e1; k += 64) {
        unsigned w = sorted[k];
        float2 v = g2[w & 0x3FFFFu];
        ax += v.x; ay += v.y;
    }
#pragma unroll
    for (int off = 32; off; off >>= 1) {
        ax += __shfl_xor(ax, off);
        ay += __shfl_xor(ay, off);
    }
    if (lane == 0) {
        float di = dinv[i];
        float2 g = g2[i];
        out[i] = make_float2(di * (ax + g.x) + b2[0],
                             di * (ay + g.y) + b2[1]);
    }
}

// ---------------- fallback path (R2-style, needs only 8 MB ws) ----------------

__global__ __launch_bounds__(256) void fb_deg(const int* __restrict__ dst, int* __restrict__ degi) {
    int e = blockIdx.x * 256 + threadIdx.x;
    if (e < N_EDGES) atomicAdd(&degi[dst[e]], 1);
}
__global__ __launch_bounds__(256) void fb_node1(const float* __restrict__ x, const int* __restrict__ degi,
                                                float* __restrict__ dinv, float2* __restrict__ u) {
    int i = blockIdx.x * 256 + threadIdx.x;
    if (i >= N_NODES) return;
    float di = rsqrtf((float)(degi[i] + 1));
    dinv[i] = di;
    float2 xi = ((const float2*)x)[i];
    u[i] = make_float2(di * xi.x, di * xi.y);
}
__global__ __launch_bounds__(256) void fb_agg(const int* __restrict__ src, const int* __restrict__ dst,
                                              const float2* __restrict__ table, float* __restrict__ acc) {
    int e = blockIdx.x * 256 + threadIdx.x;
    if (e >= N_EDGES) return;
    float2 v = table[src[e]];
    size_t d = dst[e];
    unsafeAtomicAdd(&acc[2 * d], v.x);
    unsafeAtomicAdd(&acc[2 * d + 1], v.y);
}
__global__ __launch_bounds__(256) void fb_node2(const float2* __restrict__ u, const float2* __restrict__ A1,
                                                const float* __restrict__ W1, const float* __restrict__ b1,
                                                const float* __restrict__ W2, const float* __restrict__ dinv,
                                                float2* __restrict__ g2) {
    int i = blockIdx.x * 256 + threadIdx.x;
    if (i >= N_NODES) return;
    float di = dinv[i];
    float2 a = A1[i], uu = u[i];
    float c0 = di * (a.x + uu.x), c1 = di * (a.y + uu.y);
    float a0 = 0.f, a1 = 0.f;
#pragma unroll
    for (int f = 0; f < 16; f++) {
        float o = fmaxf(c0 * W1[f] + c1 * W1[16 + f] + b1[f], 0.f);
        a0 += o * W2[2 * f];
        a1 += o * W2[2 * f + 1];
    }
    g2[i] = make_float2(di * a0, di * a1);
}
__global__ __launch_bounds__(256) void fb_node3(const float2* __restrict__ g2, const float2* __restrict__ A2,
                                                const float* __restrict__ b2, const float* __restrict__ dinv,
                                                float2* __restrict__ out) {
    int i = blockIdx.x * 256 + threadIdx.x;
    if (i >= N_NODES) return;
    float di = dinv[i];
    float2 a = A2[i], g = g2[i];
    out[i] = make_float2(di * (a.x + g.x) + b2[0], di * (a.y + g.y) + b2[1]);
}

// ---------------- launcher ----------------

extern "C" void kernel_launch(void* const* d_in, const int* in_sizes, int n_in,
                              void* d_out, int out_size, void* d_ws, size_t ws_size,
                              hipStream_t stream) {
    const float* x  = (const float*)d_in[0];
    const float* W1 = (const float*)d_in[1];
    const float* b1 = (const float*)d_in[2];
    const float* W2 = (const float*)d_in[3];
    const float* b2 = (const float*)d_in[4];
    const int* ei   = (const int*)d_in[5];   // (2,E): row 0 = src, row 1 = dst
    const int* src = ei;
    const int* dst = ei + N_EDGES;
    float2* out = (float2*)d_out;

    // ws layout (4B words), identical total to R8's proven 61.61 MB:
    //   sorted [E]                           12,800,000
    //   region [1,601,536]  -- blockHist (2048*782) during sort; after
    //       scatter: nodeStart [0..200,004) + dinv [..400,004) +
    //       u [..800,004) + g2 [..1,200,004)   (fits)
    //   bucketTotal [782] ; bucketStart [783+pad]
    const size_t need = ((size_t)N_EDGES + (size_t)SORT_BLOCKS * K_BUCKETS + 782 + 784) * 4;

    if (ws_size >= need) {
        unsigned* sorted      = (unsigned*)d_ws;
        unsigned* region      = sorted + N_EDGES;
        unsigned* blockHist   = region;
        unsigned* nodeStart   = region;                       // overlay (post-scatter)
        float*    dinv        = (float*)(region + 200004);
        float2*   u           = (float2*)(region + 400004);
        float2*   g2          = (float2*)(region + 800004);
        unsigned* bucketTotal = region + (size_t)SORT_BLOCKS * K_BUCKETS;
        unsigned* bucketStart = bucketTotal + 782;

        hist_kernel<<<SORT_BLOCKS, 256, 0, stream>>>(dst, blockHist);
        scan_perblock_kernel<<<K_BUCKETS, 256, 0, stream>>>(blockHist, bucketTotal);
        scan_buckets_kernel<<<1, 1024, 0, stream>>>(bucketTotal, bucketStart);
        scatter_kernel<<<SORT_BLOCKS, 256, 0, stream>>>(src, dst, blockHist, bucketTotal,
                                                        bucketStart, sorted);
        sortbins_kernel<<<K_BUCKETS, 256, 0, stream>>>(sorted, bucketStart, nodeStart);
        node1w_kernel<<<K_BUCKETS, 256, 0, stream>>>((const float2*)x, nodeStart, dinv, u);
        aggw1_kernel<<<(N_NODES + 3) / 4, 256, 0, stream>>>(sorted, nodeStart, u, dinv,
                                                            W1, b1, W2, g2);
        aggw2_kernel<<<(N_NODES + 3) / 4, 256, 0, stream>>>(sorted, nodeStart, g2, dinv,
                                                            b2, out);
    } else {
        // R2-style fallback (8 MB ws): global atomics, ~3.1 ms.
        float* ws = (float*)d_ws;
        int*   degi = (int*)ws;
        float* A1   = ws + N_NODES;
        float* A2   = A1 + 2 * (size_t)N_NODES;
        float* dinvF = A2 + 2 * (size_t)N_NODES;
        float2* uF  = (float2*)(dinvF + N_NODES);
        float2* g2F = uF + N_NODES;
        constexpr int EB = (N_EDGES + 255) / 256;
        constexpr int NB = (N_NODES + 255) / 256;
        (void)hipMemsetAsync(degi, 0, 5 * (size_t)N_NODES * sizeof(float), stream);
        fb_deg<<<EB, 256, 0, stream>>>(dst, degi);
        fb_node1<<<NB, 256, 0, stream>>>(x, degi, dinvF, uF);
        fb_agg<<<EB, 256, 0, stream>>>(src, dst, uF, A1);
        fb_node2<<<NB, 256, 0, stream>>>(uF, (const float2*)A1, W1, b1, W2, dinvF, g2F);
        fb_agg<<<EB, 256, 0, stream>>>(src, dst, g2F, A2);
        fb_node3<<<NB, 256, 0, stream>>>(g2F, (const float2*)A2, b2, dinvF, out);
    }
}